// Round 10
// baseline (401.039 us; speedup 1.0000x reference)
//
#include <hip/hip_runtime.h>
#include <math.h>

#define LQ 2048
#define DM 1024
#define NH 16
#define DH 64
#define UU 38
#define NBH 64            // B*NH = 4*16
#define SCALE 0.125f      // 1/sqrt(64)

typedef _Float16 f16x8 __attribute__((ext_vector_type(8)));
typedef float f32x4 __attribute__((ext_vector_type(4)));

#if __has_builtin(__builtin_amdgcn_exp2f)
#define EXP2F(x) __builtin_amdgcn_exp2f(x)
#else
#define EXP2F(x) exp2f(x)
#endif

// ---- workspace layout (bytes), total 40,700,928 (proven to fit r8/r9) ----
//   lt    : [2][64][2048][2] f64           [0, 4194304)
//   sel   : 64*38 int                       +9728
//   l3    : 64*38 f32                       +9728
//   mask  : [64][2048] s8                   +131072
//   lpart : [64][16][38] f32                +155648 (region 311296)
//   ksp   : [64][32][8192] f16 @ 7146496    (33,554,432 B)
//   opart : [64][16][38][64] f32 ALIASES ksp (stream-ordered safe: attn_pv2
//           runs strictly after attn_w_mfma's last ksp read)
#define F_OFF_SEL   4194304
#define F_OFF_L3    4204032
#define F_OFF_MASK  4213760
#define F_OFF_LPART 4344832
#define F_OFF_KSP   7146496
#define F_NEED      40700928ull

// ---------------------------------------------------------------------------
// ksplit: one-time K fp32 -> fp16 hi/lo split, conflict-free LDS image
// pre-baked (dim-block p stored at p^(k&7)). (unchanged, validated)
// ---------------------------------------------------------------------------
__global__ __launch_bounds__(256) void ksplit_kernel(const float* __restrict__ K,
                                                     _Float16* __restrict__ ksp) {
  int idx = blockIdx.x * 256 + threadIdx.x;   // 1,048,576 total
  int p = idx & 7;
  int k = (idx >> 3) & 63;
  int kc = (idx >> 9) & 31;
  int bh = idx >> 14;
  int b = bh >> 4, h = bh & 15;
  const float* src = K + ((size_t)(b * LQ + kc * 64 + k)) * DM + h * DH + (p ^ (k & 7)) * 8;
  float4 x0 = *(const float4*)src;
  float4 x1 = *(const float4*)(src + 4);
  f16x8 hi, lo;
#define KCV(i, xx) { float x_ = (xx); _Float16 hh = (_Float16)x_; hi[i] = hh; lo[i] = (_Float16)(x_ - (float)hh); }
  KCV(0, x0.x) KCV(1, x0.y) KCV(2, x0.z) KCV(3, x0.w)
  KCV(4, x1.x) KCV(5, x1.y) KCV(6, x1.z) KCV(7, x1.w)
#undef KCV
  _Float16* base = ksp + ((size_t)(bh * 32 + kc)) * 8192;
  *(f16x8*)(base + k * 64 + p * 8) = hi;
  *(f16x8*)(base + 4096 + k * 64 + p * 8) = lo;
}

// ---------------------------------------------------------------------------
// kl_mfma2: r8 structure + register prefetch of next ksp chunk (hides the
// ksp L2 read latency that sat between the two barriers). LDS 16 KB, so the
// +16 VGPR don't cliff occupancy (grid 2048 = 8 blocks/CU capacity).
// ---------------------------------------------------------------------------
__global__ __launch_bounds__(256) void kl_mfma2(const float* __restrict__ Q,
                                                const _Float16* __restrict__ ksp,
                                                double* __restrict__ lt) {
  int bh = blockIdx.x & 63;
  int qc = (blockIdx.x >> 6) & 15;
  int sp = blockIdx.x >> 10;
  int b = bh >> 4, h = bh & 15;
  int t = threadIdx.x;
  int lane = t & 63, w = t >> 6;
  int quad = lane >> 4, l15 = lane & 15;

  __shared__ __align__(16) _Float16 kbuf[8192];

  f16x8 ahi[2][2], alo[2][2];
  {
    const float* qrow = Q + ((size_t)(b * LQ + qc * 128)) * DM + h * DH;
#pragma unroll
    for (int qt = 0; qt < 2; ++qt)
#pragma unroll
      for (int c = 0; c < 2; ++c) {
        const float* p = qrow + (size_t)(w * 32 + qt * 16 + l15) * DM + c * 32 + quad * 8;
        float4 x0 = *(const float4*)p;
        float4 x1 = *(const float4*)(p + 4);
        f16x8 hi, lo;
#define QCV(i, xx) { float x_ = (xx); _Float16 hh = (_Float16)x_; hi[i] = hh; lo[i] = (_Float16)(x_ - (float)hh); }
        QCV(0, x0.x) QCV(1, x0.y) QCV(2, x0.z) QCV(3, x0.w)
        QCV(4, x1.x) QCV(5, x1.y) QCV(6, x1.z) QCV(7, x1.w)
#undef QCV
        ahi[qt][c] = hi;
        alo[qt][c] = lo;
      }
  }

  int bsw0 = quad ^ (l15 & 7);
  int bsw1 = (quad + 4) ^ (l15 & 7);
  _Float16* khi = kbuf;
  _Float16* klo = kbuf + 4096;
  const float C1 = 0.18033688011112042f;  // SCALE * log2(e)

  double l64[2][4], t64[2][4];
#pragma unroll
  for (int qt = 0; qt < 2; ++qt)
#pragma unroll
    for (int r = 0; r < 4; ++r) { l64[qt][r] = 0.0; t64[qt][r] = 0.0; }

  const uint4* gbase = (const uint4*)(ksp + ((size_t)(bh * 32 + sp * 16)) * 8192);
  uint4* lbuf = (uint4*)kbuf;

  uint4 pref[4];
#pragma unroll
  for (int i = 0; i < 4; ++i) pref[i] = gbase[i * 256 + t];

  for (int c = 0; c < 16; ++c) {
    __syncthreads();   // previous compute done reading LDS
#pragma unroll
    for (int i = 0; i < 4; ++i) lbuf[i * 256 + t] = pref[i];
    __syncthreads();
    if (c + 1 < 16) {
      const uint4* gsrc = gbase + (size_t)(c + 1) * 1024;
#pragma unroll
      for (int i = 0; i < 4; ++i) pref[i] = gsrc[i * 256 + t];
    }

    float l32[2][4], t32[2][4];
#pragma unroll
    for (int qt = 0; qt < 2; ++qt)
#pragma unroll
      for (int r = 0; r < 4; ++r) { l32[qt][r] = 0.f; t32[qt][r] = 0.f; }

#pragma unroll
    for (int kt = 0; kt < 4; ++kt) {
      int key = kt * 16 + l15;
      f16x8 bhi0 = *(const f16x8*)(khi + key * 64 + bsw0 * 8);
      f16x8 bhi1 = *(const f16x8*)(khi + key * 64 + bsw1 * 8);
      f16x8 blo0 = *(const f16x8*)(klo + key * 64 + bsw0 * 8);
      f16x8 blo1 = *(const f16x8*)(klo + key * 64 + bsw1 * 8);
#pragma unroll
      for (int qt = 0; qt < 2; ++qt) {
        f32x4 cacc = {0.f, 0.f, 0.f, 0.f};
        cacc = __builtin_amdgcn_mfma_f32_16x16x32_f16(alo[qt][0], bhi0, cacc, 0, 0, 0);
        cacc = __builtin_amdgcn_mfma_f32_16x16x32_f16(alo[qt][1], bhi1, cacc, 0, 0, 0);
        cacc = __builtin_amdgcn_mfma_f32_16x16x32_f16(ahi[qt][0], blo0, cacc, 0, 0, 0);
        cacc = __builtin_amdgcn_mfma_f32_16x16x32_f16(ahi[qt][1], blo1, cacc, 0, 0, 0);
        cacc = __builtin_amdgcn_mfma_f32_16x16x32_f16(ahi[qt][0], bhi0, cacc, 0, 0, 0);
        cacc = __builtin_amdgcn_mfma_f32_16x16x32_f16(ahi[qt][1], bhi1, cacc, 0, 0, 0);
#pragma unroll
        for (int r = 0; r < 4; ++r) {
          float rr = cacc[r];
          float e = EXP2F(rr * C1);
          l32[qt][r] += e;
          t32[qt][r] = fmaf(rr, e, t32[qt][r]);
        }
      }
    }
#pragma unroll
    for (int qt = 0; qt < 2; ++qt)
#pragma unroll
      for (int r = 0; r < 4; ++r) {
        l64[qt][r] += (double)l32[qt][r];
        t64[qt][r] += (double)t32[qt][r];
      }
  }

#pragma unroll
  for (int qt = 0; qt < 2; ++qt)
#pragma unroll
    for (int r = 0; r < 4; ++r) {
      double lv = l64[qt][r], tv = t64[qt][r];
#pragma unroll
      for (int m = 1; m < 16; m <<= 1) {
        lv += __shfl_xor(lv, m);
        tv += __shfl_xor(tv, m);
      }
      if (l15 == 0) {
        int qg = qc * 128 + w * 32 + qt * 16 + quad * 4 + r;
        double* dst = lt + ((size_t)(sp * 64 + bh) * LQ + qg) * 2;
        dst[0] = lv;
        dst[1] = tv;
      }
    }
}

// ---------------------------------------------------------------------------
// topk2: single wave per (b,h), zero barriers. (unchanged, validated)
// ---------------------------------------------------------------------------
__global__ __launch_bounds__(64) void topk2(const double* __restrict__ lt,
                                            int* __restrict__ idxout,
                                            signed char* __restrict__ selmask) {
  int bh = blockIdx.x;
  int lane = threadIdx.x;
  __shared__ double vals[LQ];
  const double logL = 7.624618986159398;
  double bv = -INFINITY;
  int bi = LQ;
  for (int j = 0; j < 32; ++j) {
    int i = j * 64 + lane;
    const double* p0 = lt + ((size_t)bh * LQ + i) * 2;
    const double* p1 = lt + ((size_t)(64 + bh) * LQ + i) * 2;
    double l = p0[0] + p1[0];
    double tt = p0[1] + p1[1];
    double v = 0.125 * (tt / l) - log(l) + logL;
    vals[i] = v;
    selmask[bh * LQ + i] = -1;
    if (v > bv) { bv = v; bi = i; }
  }
  for (int u = 0; u < UU; ++u) {
    double gv = bv;
    int gi = bi;
#pragma unroll
    for (int m = 1; m < 64; m <<= 1) {
      double ov = __shfl_xor(gv, m);
      int oi = __shfl_xor(gi, m);
      if (ov > gv || (ov == gv && oi < gi)) { gv = ov; gi = oi; }
    }
    if (lane == 0) {
      idxout[bh * UU + u] = gi;
      selmask[bh * LQ + gi] = (signed char)u;
    }
    if ((gi & 63) == lane) {
      vals[gi] = -INFINITY;
      bv = -INFINITY;
      bi = LQ;
      for (int j = 0; j < 32; ++j) {
        int i = j * 64 + lane;
        double v = vals[i];
        if (v > bv) { bv = v; bi = i; }
      }
    }
  }
}

// ---------------------------------------------------------------------------
// attn_w_mfma: r9 structure; els shrunk 48->38 rows (u<38 store guard) ->
// LDS 41.3 -> 36.2 KB -> 4 blocks/CU.
// ---------------------------------------------------------------------------
__global__ __launch_bounds__(256) void attn_w_mfma(const float* __restrict__ Q,
                                                   const _Float16* __restrict__ ksp,
                                                   const int* __restrict__ sel,
                                                   float* __restrict__ wout,
                                                   float* __restrict__ lpart) {
  int bh = blockIdx.x >> 4;
  int ks = blockIdx.x & 15;
  int b = bh >> 4, h = bh & 15;
  int t = threadIdx.x;
  int lane = t & 63, w = t >> 6;
  int quad = lane >> 4, l15 = lane & 15;

  __shared__ __align__(16) _Float16 kbuf[8192];   // 16 KB chunk image
  __shared__ float els[UU * 132];                 // 20.1 KB
  __shared__ int sidx[UU];

  if (t < UU) sidx[t] = sel[bh * UU + t];
  __syncthreads();

  f16x8 ahi[3][2], alo[3][2];
#pragma unroll
  for (int qt = 0; qt < 3; ++qt) {
    int u = qt * 16 + l15;
    if (u > 37) u = 37;
    const float* qrow = Q + ((size_t)(b * LQ + sidx[u])) * DM + h * DH;
#pragma unroll
    for (int c = 0; c < 2; ++c) {
      const float* p = qrow + c * 32 + quad * 8;
      float4 x0 = *(const float4*)p;
      float4 x1 = *(const float4*)(p + 4);
      f16x8 hi, lo;
#define QCV(i, xx) { float x_ = (xx); _Float16 hh = (_Float16)x_; hi[i] = hh; lo[i] = (_Float16)(x_ - (float)hh); }
      QCV(0, x0.x) QCV(1, x0.y) QCV(2, x0.z) QCV(3, x0.w)
      QCV(4, x1.x) QCV(5, x1.y) QCV(6, x1.z) QCV(7, x1.w)
#undef QCV
      ahi[qt][c] = hi;
      alo[qt][c] = lo;
    }
  }

  int bsw0 = quad ^ (l15 & 7);
  int bsw1 = (quad + 4) ^ (l15 & 7);
  const float C1 = 0.18033688011112042f;
  const uint4* gbase = (const uint4*)(ksp + ((size_t)(bh * 32 + ks * 2)) * 8192);
  uint4* lbuf = (uint4*)kbuf;
  _Float16* khi = kbuf;
  _Float16* klo = kbuf + 4096;

  for (int chunk = 0; chunk < 2; ++chunk) {
    __syncthreads();
#pragma unroll
    for (int i = 0; i < 4; ++i) lbuf[i * 256 + t] = gbase[chunk * 1024 + i * 256 + t];
    __syncthreads();
    int key = w * 16 + l15;
    f16x8 bhi0 = *(const f16x8*)(khi + key * 64 + bsw0 * 8);
    f16x8 bhi1 = *(const f16x8*)(khi + key * 64 + bsw1 * 8);
    f16x8 blo0 = *(const f16x8*)(klo + key * 64 + bsw0 * 8);
    f16x8 blo1 = *(const f16x8*)(klo + key * 64 + bsw1 * 8);
#pragma unroll
    for (int qt = 0; qt < 3; ++qt) {
      f32x4 cacc = {0.f, 0.f, 0.f, 0.f};
      cacc = __builtin_amdgcn_mfma_f32_16x16x32_f16(alo[qt][0], bhi0, cacc, 0, 0, 0);
      cacc = __builtin_amdgcn_mfma_f32_16x16x32_f16(alo[qt][1], bhi1, cacc, 0, 0, 0);
      cacc = __builtin_amdgcn_mfma_f32_16x16x32_f16(ahi[qt][0], blo0, cacc, 0, 0, 0);
      cacc = __builtin_amdgcn_mfma_f32_16x16x32_f16(ahi[qt][1], blo1, cacc, 0, 0, 0);
      cacc = __builtin_amdgcn_mfma_f32_16x16x32_f16(ahi[qt][0], bhi0, cacc, 0, 0, 0);
      cacc = __builtin_amdgcn_mfma_f32_16x16x32_f16(ahi[qt][1], bhi1, cacc, 0, 0, 0);
#pragma unroll
      for (int r = 0; r < 4; ++r) {
        int u = qt * 16 + quad * 4 + r;
        if (u < UU) {
          float e = EXP2F(cacc[r] * C1);
          els[u * 132 + chunk * 64 + w * 16 + l15] = e;
        }
      }
    }
  }
  __syncthreads();

  for (int i = t; i < UU * 128; i += 256) {
    int u = i >> 7, k = i & 127;
    wout[((size_t)(bh * UU + u)) * LQ + ks * 128 + k] = els[u * 132 + k];
  }

#pragma unroll
  for (int p = 0; p < 10; ++p) {
    int u = w + 4 * p;
    if (u < UU) {
      float s = els[u * 132 + lane] + els[u * 132 + 64 + lane];
#pragma unroll
      for (int m = 1; m < 64; m <<= 1) s += __shfl_xor(s, m);
      if (lane == 0) lpart[(bh * 16 + ks) * UU + u] = s;
    }
  }
}

// ---------------------------------------------------------------------------
// attn_pv2: unchanged from r9 (validated).
// ---------------------------------------------------------------------------
__global__ __launch_bounds__(256) void attn_pv2(const float* __restrict__ V,
                                                const float* __restrict__ wout,
                                                const float* __restrict__ lpart,
                                                float* __restrict__ opart,
                                                float* __restrict__ l3) {
  int bh = blockIdx.x >> 4;
  int ks = blockIdx.x & 15;
  int b = bh >> 4, h = bh & 15;
  int t = threadIdx.x;
  int d = t & 63, ug = t >> 6;

  if (ks == 0 && t < UU) {
    float s = 0.f;
#pragma unroll
    for (int i = 0; i < 16; ++i) s += lpart[(bh * 16 + i) * UU + t];
    l3[bh * UU + t] = s;
  }

  __shared__ float ps[40 * 132];
  for (int i = t; i < UU * 32; i += 256) {
    int u = i >> 5, d4 = i & 31;
    *(float4*)(ps + u * 132 + d4 * 4) =
        *(const float4*)(wout + ((size_t)(bh * UU + u)) * LQ + ks * 128 + d4 * 4);
  }
  for (int i = t; i < 2 * 132; i += 256) ps[UU * 132 + i] = 0.f;
  __syncthreads();

  const float* vbase = V + ((size_t)(b * LQ + ks * 128)) * DM + h * DH + d;
  float o[10];
#pragma unroll
  for (int p = 0; p < 10; ++p) o[p] = 0.f;

  for (int j4 = 0; j4 < 128; j4 += 4) {
    float v0 = vbase[(size_t)(j4 + 0) * DM];
    float v1 = vbase[(size_t)(j4 + 1) * DM];
    float v2 = vbase[(size_t)(j4 + 2) * DM];
    float v3 = vbase[(size_t)(j4 + 3) * DM];
#pragma unroll
    for (int p = 0; p < 10; ++p) {
      float4 pw = *(const float4*)(ps + (ug + 4 * p) * 132 + j4);
      o[p] = fmaf(pw.x, v0, o[p]);
      o[p] = fmaf(pw.y, v1, o[p]);
      o[p] = fmaf(pw.z, v2, o[p]);
      o[p] = fmaf(pw.w, v3, o[p]);
    }
  }

#pragma unroll
  for (int p = 0; p < 10; ++p) {
    int u = ug + 4 * p;
    if (u < UU) opart[((size_t)((bh * 16 + ks) * UU + u)) * DH + d] = o[p];
  }
}

// ---------------------------------------------------------------------------
// writeout: float4-vectorized (4 elems/thread, grid 52k -> 13k blocks).
// Part 1: N1/4 float4s normalize wout. Part 2: 2,097,152 float4s write the
// full dense output (zeros or 16-partial opart reduce).
// ---------------------------------------------------------------------------
__global__ __launch_bounds__(256) void writeout_kernel(const signed char* __restrict__ selmask,
                                                       const float* __restrict__ l3,
                                                       const float* __restrict__ opart,
                                                       float* __restrict__ out,
                                                       float* __restrict__ wout) {
  const int N1v = (NBH * UU * LQ) / 4;    // 1,245,184 float4s
  int i = blockIdx.x * 256 + threadIdx.x;
  if (i < N1v) {
    float inv = 1.0f / l3[i >> 9];        // bhu = (i*4) >> 11
    float4 v = ((const float4*)wout)[i];
    v.x *= inv; v.y *= inv; v.z *= inv; v.w *= inv;
    ((float4*)wout)[i] = v;
  } else {
    int i2 = i - N1v;                     // float4 index into out [B,L,H,DH/4]
    if (i2 < (4 * LQ * DM) / 4) {
      int h = (i2 >> 4) & 15;
      int q = (i2 >> 8) & 2047;
      int b = i2 >> 19;
      int bh = b * 16 + h;
      int u = selmask[bh * LQ + q];
      float4 val = make_float4(0.f, 0.f, 0.f, 0.f);
      if (u >= 0) {
        int d4 = i2 & 15;
        float4 s = make_float4(0.f, 0.f, 0.f, 0.f);
#pragma unroll
        for (int p = 0; p < 16; ++p) {
          float4 t4 = *(const float4*)(opart + ((size_t)((bh * 16 + p) * UU + u)) * DH + d4 * 4);
          s.x += t4.x; s.y += t4.y; s.z += t4.z; s.w += t4.w;
        }
        float inv = 1.0f / l3[bh * UU + u];
        val = make_float4(s.x * inv, s.y * inv, s.z * inv, s.w * inv);
      }
      ((float4*)out)[i2] = val;
    }
  }
}

extern "C" void kernel_launch(void* const* d_in, const int* in_sizes, int n_in,
                              void* d_out, int out_size, void* d_ws, size_t ws_size,
                              hipStream_t stream) {
  (void)in_sizes; (void)n_in;
  if (ws_size < F_NEED) return;   // fail visibly over UB; r8/r9 confirmed fit
  const float* Q = (const float*)d_in[0];
  const float* K = (const float*)d_in[1];
  const float* V = (const float*)d_in[2];
  float* out = (float*)d_out;
  float* wout = out + (size_t)4 * LQ * DM;
  char* ws = (char*)d_ws;

  double* lt = (double*)ws;
  int* sel = (int*)(ws + F_OFF_SEL);
  float* l3 = (float*)(ws + F_OFF_L3);
  signed char* mask = (signed char*)(ws + F_OFF_MASK);
  float* lpart = (float*)(ws + F_OFF_LPART);
  _Float16* ksp = (_Float16*)(ws + F_OFF_KSP);
  float* opart = (float*)(ws + F_OFF_KSP);   // aliases ksp, stream-ordered safe

  ksplit_kernel<<<4096, 256, 0, stream>>>(K, ksp);
  kl_mfma2<<<2048, 256, 0, stream>>>(Q, ksp, lt);
  topk2<<<NBH, 64, 0, stream>>>(lt, sel, mask);
  attn_w_mfma<<<NBH * 16, 256, 0, stream>>>(Q, ksp, sel, wout, lpart);
  attn_pv2<<<NBH * 16, 256, 0, stream>>>(V, wout, lpart, opart, l3);
  int nv = (NBH * UU * LQ) / 4 + (4 * LQ * DM) / 4;
  writeout_kernel<<<(nv + 255) / 256, 256, 0, stream>>>(mask, l3, opart, out, wout);
}